// Round 3
// baseline (205.337 us; speedup 1.0000x reference)
//
#include <hip/hip_runtime.h>
#include <math.h>

// Problem constants (B=4, T=2048, C=576, H=12, D=48)
#define Bn 4
#define Tn 2048
#define Cn 576
#define Hn 12
#define Dn 48
#define Mn (Bn*Tn)          // 8192 rows

// log2(e) / sqrt(48) — folded into q so attention uses exp2 directly
#define QSCALE (1.4426950408889634f * 0.14433756729740643f)

typedef short  short8  __attribute__((ext_vector_type(8)));   // 8 bf16 (4 VGPRs)
typedef float  floatx4 __attribute__((ext_vector_type(4)));   // MFMA acc
typedef unsigned short ushort_t;
typedef unsigned short ushort8_t __attribute__((ext_vector_type(8))); // 16B

static __device__ __forceinline__ unsigned short f2bf(float f) {
    union { float f; unsigned int u; } v; v.f = f;
    unsigned int r = v.u + 0x7FFFu + ((v.u >> 16) & 1u);   // round-to-nearest-even
    return (unsigned short)(r >> 16);
}

// truncation-pack two fp32 -> packed bf16x2 (P >= 0, rel err <= 2^-8)
static __device__ __forceinline__ unsigned int pack_trunc(float a, float b) {
    union { float f; unsigned int u; } ua, ub; ua.f = a; ub.f = b;
    return (ua.u >> 16) | (ub.u & 0xFFFF0000u);
}

// async global->LDS, 16B per lane (attn only now; GEMMs load fragments direct)
static __device__ __forceinline__ void gload16(void* lds, const void* g) {
    __builtin_amdgcn_global_load_lds(
        (const __attribute__((address_space(1))) void*)g,
        (__attribute__((address_space(3))) void*)lds, 16, 0, 0);
}

// ---------------------------------------------------------------------------
// fused fp32 -> bf16 cast of all three inputs (one launch) + zb zeroing
// ---------------------------------------------------------------------------
__global__ __launch_bounds__(256)
void cast3(const float* __restrict__ a, ushort_t* __restrict__ oa, int na4,
           const float* __restrict__ b, ushort_t* __restrict__ ob, int nb4,
           const float* __restrict__ c, ushort_t* __restrict__ oc, int nc4,
           ushort_t* __restrict__ zb)
{
    int i = blockIdx.x * 256 + threadIdx.x;
    if (blockIdx.x == 0 && threadIdx.x < 16) {
        float4 z = (float4){0.f, 0.f, 0.f, 0.f};
        ((float4*)zb)[threadIdx.x] = z;          // 256 B of zeros
    }
    const float* src; ushort_t* dst; int idx;
    if (i < na4)                  { src = a; dst = oa; idx = i; }
    else if (i < na4 + nb4)       { src = b; dst = ob; idx = i - na4; }
    else if (i < na4 + nb4 + nc4) { src = c; dst = oc; idx = i - na4 - nb4; }
    else return;
    float4 v = ((const float4*)src)[idx];
    ushort4 o;
    o.x = f2bf(v.x); o.y = f2bf(v.y); o.z = f2bf(v.z); o.w = f2bf(v.w);
    ((ushort4*)dst)[idx] = o;
}

// ---------------------------------------------------------------------------
// ROUND-11 QKV GEMM: DIRECT-LOAD register GEMM (no LDS staging, no barriers
// in the main loop).  Rationale: r0/r1/r2 showed ~49-53us for ANY
// global_load_lds-staged schedule (2-buf, 4-buf counted, full 8-phase) with
// all pipes <15% busy -> the per-CU global->LDS DMA path itself is the
// bottleneck (~100-185 cy per 1KB wave-op, shallow queue).  Fragments are
// loaded straight from L2 into VGPRs via global_load_dwordx4 (deep VMEM
// pipelining).  Cost: A read 4x, B read 2x per block = 1.77MB/block from L2
// (~31K cy at 56B/cy/CU) vs 49.5us measured for the DMA version.
// Tile 256x256, 8 waves (2M x 4N), wave-tile 128x64, K swept in 18 halves
// of 32.  Grid 224 = 8 XCD x (4m x 7n), N padded 1728->1792 (pad rows read
// the adjacent wpb buffer, outputs discarded).  LDS only for the coalescing
// epilogue (q/k row-major, v transposed for [B,H,48,T]).
// ---------------------------------------------------------------------------
__global__ __launch_bounds__(512)
void gemm_qkv(const ushort_t* __restrict__ A, const ushort_t* __restrict__ W,
              ushort_t* __restrict__ outb)
{
    __shared__ __align__(16) ushort_t Lc[34816];   // max(256*136, 128*264)

    const int tid  = threadIdx.x;
    const int wave = tid >> 6;
    const int lane = tid & 63;
    const int m    = lane & 15;
    const int g    = lane >> 4;
    const int wr   = wave >> 2;      // m-half 0..1 (128 rows)
    const int wn   = wave & 3;       // n-quarter 0..3 (64 cols)

    const int bid  = blockIdx.x;
    const int xcd  = bid & 7;
    const int slot = bid >> 3;       // 0..27
    const int ng   = slot % 7;
    const int mg   = xcd + 8 * (slot / 7);
    const int m0   = mg * 256;
    const int n0g  = ng * 256;

    // per-lane fragment base pointers (ushort units); frag (mf/nf, half h):
    //   A[(m0 + wr*128 + mf*16 + m) * 576 + h*32 + g*8]  (16B = 8 bf16)
    const ushort_t* Ab = A + (size_t)(m0  + wr * 128 + m) * Cn + g * 8;
    const ushort_t* Wb = W + (size_t)(n0g + wn * 64  + m) * Cn + g * 8;

    floatx4 acc[8][4];
    #pragma unroll
    for (int i = 0; i < 8; ++i)
        #pragma unroll
        for (int j = 0; j < 4; ++j)
            acc[i][j] = (floatx4){0.f, 0.f, 0.f, 0.f};

    // 18 K-halves of 32; unroll 2 so the compiler hoists next-half loads
    // under the current half's MFMAs without blowing VGPR budget.
    #pragma unroll 2
    for (int h = 0; h < 18; ++h) {
        short8 af[8], bf[4];
        #pragma unroll
        for (int mf = 0; mf < 8; ++mf)
            af[mf] = *(const short8*)(Ab + (size_t)mf * 16 * Cn + h * 32);
        #pragma unroll
        for (int nf = 0; nf < 4; ++nf)
            bf[nf] = *(const short8*)(Wb + (size_t)nf * 16 * Cn + h * 32);
        #pragma unroll
        for (int mf = 0; mf < 8; ++mf)
            #pragma unroll
            for (int nf = 0; nf < 4; ++nf)
                acc[mf][nf] = __builtin_amdgcn_mfma_f32_16x16x32_bf16(
                    af[mf], bf[nf], acc[mf][nf], 0, 0, 0);
    }

    // ---- epilogue: acc[mf][nf] row = m0+wr*128+mf*16+g*4+r, col(n-local) =
    //      wn*64+nf*16+m.  Two 128-col halves; v-halves staged transposed. ----
    const size_t per = (size_t)Bn * Hn * Tn * Dn;
    const int b  = m0 >> 11;
    const int t0 = m0 & 2047;

    __syncthreads();   // all waves done with MFMA before Lc use (paranoia-cheap)

    #pragma unroll
    for (int h2 = 0; h2 < 2; ++h2) {
        const int  nbase = n0g + h2 * 128;     // first global n of this half
        const bool vmode = (nbase >= 1152);    // 1152 = 9*128: half-uniform
        if ((wn >> 1) == h2) {
            if (!vmode) {
                // row-major Lq[256][136]
                #pragma unroll
                for (int mf = 0; mf < 8; ++mf)
                    #pragma unroll
                    for (int nf = 0; nf < 4; ++nf) {
                        const int  nfb = n0g + wn * 64 + nf * 16;   // frag n base
                        const float sc = (nfb < 576) ? QSCALE : 1.0f;
                        const int col = (wn & 1) * 64 + nf * 16 + m;
                        const int rb  = wr * 128 + mf * 16 + g * 4;
                        #pragma unroll
                        for (int r = 0; r < 4; ++r)
                            Lc[(rb + r) * 136 + col] = f2bf(acc[mf][nf][r] * sc);
                    }
            } else {
                // transposed Lv[128][264]
                #pragma unroll
                for (int mf = 0; mf < 8; ++mf)
                    #pragma unroll
                    for (int nf = 0; nf < 4; ++nf) {
                        const int col = (wn & 1) * 64 + nf * 16 + m;
                        const int rb  = wr * 128 + mf * 16 + g * 4;
                        ushort4 pk;
                        pk.x = f2bf(acc[mf][nf][0]); pk.y = f2bf(acc[mf][nf][1]);
                        pk.z = f2bf(acc[mf][nf][2]); pk.w = f2bf(acc[mf][nf][3]);
                        *(ushort4*)&Lc[col * 264 + rb] = pk;
                    }
            }
        }
        __syncthreads();
        if (!vmode) {
            // q/k: [B,H,T,48]; 16B chunks along d (8|48 -> no head straddle)
            #pragma unroll
            for (int it = 0; it < 8; ++it) {
                const int c   = tid + it * 512;
                const int row = c >> 4;
                const int c8  = (c & 15) * 8;
                const int n   = nbase + c8;
                const int which = (n >= 576);
                const int nn  = n - which * 576;
                const int h   = nn / 48, d = nn - h * 48;
                ushort_t* dst = outb + (size_t)which * per
                    + ((size_t)(b * Hn + h) * Tn + t0 + row) * Dn + d;
                *(ushort8_t*)dst = *(const ushort8_t*)&Lc[row * 136 + c8];
            }
        } else {
            // v: [B,H,48,T]; 16B chunks along t; skip pad cols (n >= 1728)
            #pragma unroll
            for (int it = 0; it < 8; ++it) {
                const int c   = tid + it * 512;
                const int col = c >> 5;
                const int rc  = (c & 31) * 8;
                const int n   = nbase + col;
                if (n < 1728) {
                    const int dd = n - 1152;
                    const int h  = dd / 48, d = dd - h * 48;
                    ushort_t* dst = outb + 2 * per
                        + ((size_t)(b * Hn + h) * Dn + d) * Tn + t0 + rc;
                    *(ushort8_t*)dst = *(const ushort8_t*)&Lc[col * 264 + rc];
                }
            }
        }
        __syncthreads();
    }
}

// ---------------------------------------------------------------------------
// ROUND-11 proj GEMM: same direct-load register GEMM, fp32 output.
// out = A[8192,576] @ W[576,576]^T.  Tile 128x192, 8 waves (2M x 4N),
// wave-tile 64x48 (mf=4, nf=3).  Grid 192 = 8 XCD x (8m x 3n).
// ---------------------------------------------------------------------------
__global__ __launch_bounds__(512)
void gemm_proj(const ushort_t* __restrict__ A, const ushort_t* __restrict__ W,
               float* __restrict__ outf)
{
    const int tid  = threadIdx.x;
    const int wave = tid >> 6;
    const int lane = tid & 63;
    const int m    = lane & 15;
    const int g    = lane >> 4;
    const int wr   = wave >> 2;      // m-half 0..1 (64 rows)
    const int wn   = wave & 3;       // n-quarter 0..3 (48 cols)

    const int bid  = blockIdx.x;
    const int xcd  = bid & 7;
    const int slot = bid >> 3;       // 0..23
    const int ng   = slot % 3;
    const int mg   = xcd + 8 * (slot / 3);   // 0..63
    const int m0   = mg * 128;
    const int n0   = ng * 192 + wn * 48;

    const ushort_t* Ab = A + (size_t)(m0 + wr * 64 + m) * Cn + g * 8;
    const ushort_t* Wb = W + (size_t)(n0 + m) * Cn + g * 8;

    floatx4 acc[4][3];
    #pragma unroll
    for (int i = 0; i < 4; ++i)
        #pragma unroll
        for (int j = 0; j < 3; ++j)
            acc[i][j] = (floatx4){0.f, 0.f, 0.f, 0.f};

    #pragma unroll 2
    for (int h = 0; h < 18; ++h) {
        short8 af[4], bf[3];
        #pragma unroll
        for (int mf = 0; mf < 4; ++mf)
            af[mf] = *(const short8*)(Ab + (size_t)mf * 16 * Cn + h * 32);
        #pragma unroll
        for (int nf = 0; nf < 3; ++nf)
            bf[nf] = *(const short8*)(Wb + (size_t)nf * 16 * Cn + h * 32);
        #pragma unroll
        for (int mf = 0; mf < 4; ++mf)
            #pragma unroll
            for (int nf = 0; nf < 3; ++nf)
                acc[mf][nf] = __builtin_amdgcn_mfma_f32_16x16x32_bf16(
                    af[mf], bf[nf], acc[mf][nf], 0, 0, 0);
    }

    // direct fp32 store: 16-lane runs of 64B along n
    #pragma unroll
    for (int mf = 0; mf < 4; ++mf) {
        #pragma unroll
        for (int r = 0; r < 4; ++r) {
            const int mrow = m0 + wr * 64 + mf * 16 + g * 4 + r;
            #pragma unroll
            for (int nf = 0; nf < 3; ++nf)
                outf[(size_t)mrow * Cn + n0 + nf * 16 + m] = acc[mf][nf][r];
        }
    }
}

// ---------------------------------------------------------------------------
// Flash attention via S^T, no-max softmax, bf16 MFMA (round-7 kernel,
// round-9 interleaved-qt grid).  UNCHANGED this round: it is the
// confirmation target for the DMA-serialization theory next round.
// ---------------------------------------------------------------------------
__global__ __launch_bounds__(512, 6)
void attn_mfma(const ushort_t* __restrict__ Q, const ushort_t* __restrict__ K,
               const ushort_t* __restrict__ V, ushort_t* __restrict__ Y,
               const ushort_t* __restrict__ zb)
{
    __shared__ __align__(16) ushort_t QPs[16][512];    // Q tile, then reused as P^T
    __shared__ __align__(16) ushort_t Ks[2][8][512];   // [buf][(ktile t, kc)]
    __shared__ __align__(16) ushort_t Vs[2][6][512];   // [buf][(dtile t, kc)]

    const int id   = blockIdx.x;
    const int kk   = id / 48;
    const int bh   = id - kk * 48;
    const int QT   = (kk & 1) ? (kk >> 1) : (15 - (kk >> 1));   // interleave big/small
    const int tid  = threadIdx.x;
    const int wave = tid >> 6;       // 0..7
    const int lane = tid & 63;
    const int m    = lane & 15;
    const int g    = lane >> 4;
    const int q0   = QT * 128;
    const int nkt  = 2 * QT + 2;     // 64-row K tiles to process

    const ushort_t* Qp = Q + (size_t)bh * Tn * Dn;
    const ushort_t* Kp = K + (size_t)bh * Tn * Dn;
    const ushort_t* Vp = V + (size_t)bh * Dn * Tn;     // [48][T]

    {
        const char* qrp = (const char*)(Qp + (size_t)(q0 + wave * 16 + m) * Dn);
        gload16(&QPs[wave * 2 + 0][0], qrp + g * 16);
        gload16(&QPs[wave * 2 + 1][0], (g < 2) ? (qrp + 64 + g * 16) : (const char*)zb);
    }

    const bool  kpad = ((wave & 1) == 1) && (g >= 2);
    const char* kptr = kpad ? (const char*)zb
        : (const char*)(Kp + (size_t)((wave >> 1) * 16 + m) * Dn) + (wave & 1) * 64 + g * 16;
    const int   kadv = kpad ? 0 : 64 * Dn * 2;         // 64 K-rows per tile
    const char* vptr = (const char*)(Vp + (size_t)((wave >> 1) * 16 + m) * Tn)
                       + (wave & 1) * 64 + g * 16;     // valid only for wave<6
    const int   vadv = 64 * 2;                         // 64 V^T-cols per tile

    gload16(&Ks[0][wave][0], kptr); kptr += kadv;
    if (wave < 6) { gload16(&Vs[0][wave][0], vptr); vptr += vadv; }
    __syncthreads();   // drains vmcnt -> Q + tile0 ready

    short8 bq[2];
    bq[0] = *(const short8*)&QPs[wave * 2 + 0][lane * 8];
    bq[1] = *(const short8*)&QPs[wave * 2 + 1][lane * 8];

    floatx4 acc[3];
    #pragma unroll
    for (int t = 0; t < 3; ++t) acc[t] = (floatx4){0.f, 0.f, 0.f, 0.f};
    float l_tot = 0.f;
    const int qrow  = q0 + wave * 16 + m;
    const int qwmin = q0 + wave * 16;
    const int qwmax = qwmin + 15;

    for (int jt = 0; jt < nkt; ++jt) {
        const int cur = jt & 1;
        const int j0  = jt * 64;
        if (jt + 1 < nkt) {
            gload16(&Ks[cur ^ 1][wave][0], kptr); kptr += kadv;
            if (wave < 6) { gload16(&Vs[cur ^ 1][wave][0], vptr); vptr += vadv; }
        }

        if (j0 <= qwmax) {
            floatx4 s[4];
            #pragma unroll
            for (int t = 0; t < 4; ++t) {
                s[t] = (floatx4){0.f, 0.f, 0.f, 0.f};
                #pragma unroll
                for (int kc = 0; kc < 2; ++kc) {
                    short8 ak = *(const short8*)&Ks[cur][t * 2 + kc][lane * 8];
                    s[t] = __builtin_amdgcn_mfma_f32_16x16x32_bf16(ak, bq[kc], s[t], 0, 0, 0);
                }
            }

            float p[4][4];
            float lsum = 0.f;
            if (j0 + 63 > qwmin) {
                #pragma unroll
                for (int t = 0; t < 4; ++t)
                    #pragma unroll
                    for (int r = 0; r < 4; ++r) {
                        int j = j0 + t * 16 + g * 4 + r;
                        float v = (j <= qrow) ? s[t][r] : -1e30f;
                        float e = __builtin_amdgcn_exp2f(v);
                        p[t][r] = e; lsum += e;
                    }
            } else {
                #pragma unroll
                for (int t = 0; t < 4; ++t)
                    #pragma unroll
                    for (int r = 0; r < 4; ++r) {
                        float e = __builtin_amdgcn_exp2f(s[t][r]);
                        p[t][r] = e; lsum += e;
                    }
            }
            lsum += __shfl_xor(lsum, 16);
            lsum += __shfl_xor(lsum, 32);
            l_tot += lsum;

            #pragma unroll
            for (int t = 0; t < 4; ++t) {
                uint2 w2;
                w2.x = pack_trunc(p[t][0], p[t][1]);
                w2.y = pack_trunc(p[t][2], p[t][3]);
                *(uint2*)&QPs[wave * 2 + (t >> 1)]
                             [(2 * (t & 1) + (g >> 1)) * 128 + m * 8 + (g & 1) * 4] = w2;
            }
            asm volatile("s_waitcnt lgkmcnt(0)" ::: "memory");

            #pragma unroll
            for (int kc = 0; kc < 2; ++kc) {
                short8 bp = *(const short8*)&QPs[wave * 2 + kc][lane * 8];
                #pragma unroll
                for (int t = 0; t < 3; ++t) {
                    short8 av = *(const short8*)&Vs[cur][t * 2 + kc][lane * 8];
                    acc[t] = __builtin_amdgcn_mfma_f32_16x16x32_bf16(av, bp, acc[t], 0, 0, 0);
                }
            }
        }

        __syncthreads();
    }

    const float inv = 1.0f / l_tot;
    const int b = bh / Hn;
    const int h = bh - b * Hn;
    ushort_t* yp = Y + ((size_t)(b * Tn + qrow)) * Cn + h * Dn;
    #pragma unroll
    for (int t = 0; t < 3; ++t) {
        ushort4 o;
        o.x = f2bf(acc[t][0] * inv);
        o.y = f2bf(acc[t][1] * inv);
        o.z = f2bf(acc[t][2] * inv);
        o.w = f2bf(acc[t][3] * inv);
        *(ushort4*)&yp[t * 16 + g * 4] = o;
    }
}

// ---------------------------------------------------------------------------
extern "C" void kernel_launch(void* const* d_in, const int* in_sizes, int n_in,
                              void* d_out, int out_size, void* d_ws, size_t ws_size,
                              hipStream_t stream)
{
    const float* x      = (const float*)d_in[0];   // [B,T,C]
    const float* w_qkv  = (const float*)d_in[1];   // [3C,C]
    const float* w_proj = (const float*)d_in[2];   // [C,C]
    float* out = (float*)d_out;                    // [B,T,C] fp32

    const size_t per = (size_t)Bn * Hn * Tn * Dn;  // 4,718,592

    ushort_t* xb  = (ushort_t*)d_ws;               // 8192*576
    ushort_t* wqb = xb  + (size_t)Mn * Cn;         // 1728*576 (+64 pad rows read into wpb)
    ushort_t* wpb = wqb + (size_t)3 * Cn * Cn;     // 576*576
    ushort_t* qkv = wpb + (size_t)Cn * Cn;         // 3*per (q | k | v^T)
    ushort_t* yb  = qkv + 3 * per;                 // 8192*576
    ushort_t* zb  = yb  + (size_t)Mn * Cn;         // 256 B of zeros (Q/K pad source)

    // fused casts (fp32 -> bf16) + zb zeroing
    const int na4 = Mn * Cn / 4, nb4 = 3 * Cn * Cn / 4, nc4 = Cn * Cn / 4;
    cast3<<<dim3((na4 + nb4 + nc4 + 255) / 256), dim3(256), 0, stream>>>(
        x, xb, na4, w_qkv, wqb, nb4, w_proj, wpb, nc4, zb);

    // QKV GEMM (M=8192, N=1792 padded): 224 blocks, direct-load reg GEMM
    gemm_qkv<<<dim3(224), dim3(512), 0, stream>>>(xb, wqb, qkv);

    // causal attention (ALiBi bias is exactly zero on the unmasked region)
    attn_mfma<<<dim3((Tn / 128) * Bn * Hn), dim3(512), 0, stream>>>(
        qkv, qkv + per, qkv + 2 * per, yb, zb);

    // output projection (M=8192, N=576) -> fp32: 192 blocks, direct-load
    gemm_proj<<<dim3(192), dim3(512), 0, stream>>>(yb, wpb, out);
}